// Round 8
// baseline (475.161 us; speedup 1.0000x reference)
//
#include <hip/hip_runtime.h>
#include <hip/hip_bf16.h>
#include <math.h>

#define B_ 2
#define T_ 2048
#define D_ 2048
#define H_ 16
#define KV_ 4
#define HD_ 128
#define REP_ 4
#define QKVSTR 3072

typedef __attribute__((ext_vector_type(8))) short s16x8;
typedef __attribute__((ext_vector_type(4))) float f32x4;
typedef __hip_bfloat16 bf16;

__device__ __forceinline__ short f2bf(float x) {
    bf16 h = __float2bfloat16(x);
    return *reinterpret_cast<short*>(&h);
}

__device__ __forceinline__ void gl2lds16(const void* g, void* l) {
    __builtin_amdgcn_global_load_lds(
        (const __attribute__((address_space(1))) char*)g,
        (__attribute__((address_space(3))) char*)l, 16, 0, 0);
}

// ---------------- fused prep: cast x -> bf16  +  all 4 weight transposes ----
// blocks [0,4096): cast; [4096,5120): Wq; [5120,5376): Wk; [5376,5632): Wv;
// [5632,6656): Wo. All weights have K=2048 rows.
__global__ __launch_bounds__(256) void prep(const float* __restrict__ x,
                                            const float* __restrict__ Wq,
                                            const float* __restrict__ Wk,
                                            const float* __restrict__ Wv,
                                            const float* __restrict__ Wo,
                                            bf16* __restrict__ xb,
                                            bf16* __restrict__ Wqkvt,
                                            bf16* __restrict__ Wot,
                                            float qscale) {
    const int bid = blockIdx.x;
    const int t = threadIdx.x;
    if (bid < 4096) {
        int i = (bid * 256 + t) * 8;
        float4 a = *(const float4*)(x + i);
        float4 b = *(const float4*)(x + i + 4);
        short o[8] = {f2bf(a.x), f2bf(a.y), f2bf(a.z), f2bf(a.w),
                      f2bf(b.x), f2bf(b.y), f2bf(b.z), f2bf(b.w)};
        *(s16x8*)(xb + i) = *(const s16x8*)o;
        return;
    }
    __shared__ short tile[64 * 72];
    const float* W; bf16* dst; int N; float scale; int seg;
    if (bid < 5120)      { seg = bid - 4096; W = Wq; dst = Wqkvt;                      N = 2048; scale = qscale; }
    else if (bid < 5376) { seg = bid - 5120; W = Wk; dst = Wqkvt + (size_t)2048 * D_;  N = 512;  scale = 1.f; }
    else if (bid < 5632) { seg = bid - 5376; W = Wv; dst = Wqkvt + (size_t)2560 * D_;  N = 512;  scale = 1.f; }
    else                 { seg = bid - 5632; W = Wo; dst = Wot;                        N = 2048; scale = 1.f; }
    const int k0 = (seg & 31) * 64, n0 = (seg >> 5) * 64;
    const int r = t >> 2, c0 = (t & 3) * 16;
    const float* src = W + (size_t)(k0 + r) * N + n0 + c0;
    #pragma unroll
    for (int i = 0; i < 16; i += 4) {
        float4 v = *(const float4*)(src + i);
        tile[r * 72 + c0 + i + 0] = f2bf(v.x * scale);
        tile[r * 72 + c0 + i + 1] = f2bf(v.y * scale);
        tile[r * 72 + c0 + i + 2] = f2bf(v.z * scale);
        tile[r * 72 + c0 + i + 3] = f2bf(v.w * scale);
    }
    __syncthreads();
    short tmp[16];
    #pragma unroll
    for (int i = 0; i < 16; ++i) tmp[i] = tile[(c0 + i) * 72 + r];
    bf16* d = dst + (size_t)(n0 + r) * D_ + k0 + c0;
    *(s16x8*)(d)     = *(const s16x8*)&tmp[0];
    *(s16x8*)(d + 8) = *(const s16x8*)&tmp[8];
}

// ---------------- transpose V: Vtg[(b*KV+g)*128+d][t] = V[b*T+t][g*128+d] ----
__global__ __launch_bounds__(256) void transpose_v(const bf16* __restrict__ V,
                                                   bf16* __restrict__ Vtg) {
    __shared__ short tile[64 * 72];
    const int t0 = blockIdx.x * 64;
    const int g = blockIdx.y >> 1;
    const int dp = (blockIdx.y & 1) * 64;
    const int b = blockIdx.z;
    const int t = threadIdx.x;
    const int r = t >> 2, c0 = (t & 3) * 16;
    const bf16* src = V + (size_t)(b * T_ + t0 + r) * QKVSTR + g * HD_ + dp + c0;
    *(s16x8*)&tile[r * 72 + c0]     = *(const s16x8*)(src);
    *(s16x8*)&tile[r * 72 + c0 + 8] = *(const s16x8*)(src + 8);
    __syncthreads();
    const int d = t >> 2, tc = (t & 3) * 16;
    short tmp[16];
    #pragma unroll
    for (int i = 0; i < 16; ++i) tmp[i] = tile[(tc + i) * 72 + d];
    bf16* dst = Vtg + (size_t)((b * KV_ + g) * HD_ + dp + d) * T_ + t0 + tc;
    *(s16x8*)(dst)     = *(const s16x8*)&tmp[0];
    *(s16x8*)(dst + 8) = *(const s16x8*)&tmp[8];
}

// ---------------- bf16 NT GEMM: C[M,N] = A[M,K] * Bt[N,K]^T ----------------
template<typename OUTT, int ROUND>
__global__ __launch_bounds__(256) void gemm_nt(const bf16* __restrict__ A,
                                               const bf16* __restrict__ Bt,
                                               OUTT* __restrict__ C,
                                               int M, int N, int K) {
    __shared__ short As[128 * 64];
    __shared__ short Bs[128 * 64];
    const int tid = threadIdx.x;
    const int lane = tid & 63;
    const int wave = tid >> 6;
    const int quad = lane >> 4;
    const int l16 = lane & 15;
    const int wr = wave >> 1, wc = wave & 1;
    const int row0 = blockIdx.y * 128;
    const int col0 = blockIdx.x * 128;

    f32x4 acc[4][4] = {};

    for (int k0 = 0; k0 < K; k0 += 64) {
        __syncthreads();
        #pragma unroll
        for (int i = 0; i < 4; ++i) {
            int g = i * 256 + tid;
            int row = g >> 3;
            int cs = (g & 7) ^ (row & 7);
            gl2lds16(A + (size_t)(row0 + row) * K + k0 + cs * 8, &As[g * 8]);
        }
        #pragma unroll
        for (int i = 0; i < 4; ++i) {
            int g = i * 256 + tid;
            int row = g >> 3;
            int cs = (g & 7) ^ (row & 7);
            gl2lds16(Bt + (size_t)(col0 + row) * K + k0 + cs * 8, &Bs[g * 8]);
        }
        __syncthreads();
        #pragma unroll
        for (int kk = 0; kk < 2; ++kk) {
            s16x8 af[4], bfr[4];
            #pragma unroll
            for (int i = 0; i < 4; ++i) {
                int row = wr * 64 + i * 16 + l16;
                int c = (kk * 4 + quad) ^ (row & 7);
                af[i] = *(const s16x8*)&As[row * 64 + c * 8];
            }
            #pragma unroll
            for (int j = 0; j < 4; ++j) {
                int row = wc * 64 + j * 16 + l16;
                int c = (kk * 4 + quad) ^ (row & 7);
                bfr[j] = *(const s16x8*)&Bs[row * 64 + c * 8];
            }
            #pragma unroll
            for (int i = 0; i < 4; ++i)
                #pragma unroll
                for (int j = 0; j < 4; ++j)
                    acc[i][j] = __builtin_amdgcn_mfma_f32_16x16x32_bf16(
                        af[i], bfr[j], acc[i][j], 0, 0, 0);
        }
    }

    #pragma unroll
    for (int i = 0; i < 4; ++i) {
        #pragma unroll
        for (int j = 0; j < 4; ++j) {
            #pragma unroll
            for (int r = 0; r < 4; ++r) {
                int row = row0 + wr * 64 + i * 16 + quad * 4 + r;
                int col = col0 + wc * 64 + j * 16 + l16;
                float v = acc[i][j][r];
                if (ROUND) v = rintf(v * 1e4f) * 1e-4f;
                if constexpr (sizeof(OUTT) == 2)
                    C[(size_t)row * N + col] = __float2bfloat16(v);
                else
                    C[(size_t)row * N + col] = v;
            }
        }
    }
}

// ---------------- MFMA flash attention v4 ----------------
// BQ=128 (32 q-rows/wave via rt=2), BKV=64, static softmax (exp2, no max).
// grid (H, 32): b = by&1, qt = 15-(by>>1) [heavy first]. Same 36 ds_read_b128
// per wave-tile as v3 now feed 64 MFMAs -> per-q LDS traffic halved.
__global__ __launch_bounds__(256, 3) void flash4(const bf16* __restrict__ Q,
                                                 const bf16* __restrict__ K,
                                                 const bf16* __restrict__ Vtg,
                                                 bf16* __restrict__ O) {
    __shared__ short Kt[64 * 128];     // 16 KB
    __shared__ short Vt[128 * 64];     // 16 KB
    __shared__ short PsOb[128 * 72];   // 18 KB; Ps view 128x72, Ob view 64x136
    __shared__ float lbuf[4][32];

    const int h = blockIdx.x;
    const int b = blockIdx.y & 1;
    const int qt = 15 - (blockIdx.y >> 1);
    const int g = h >> 2;
    const int tid = threadIdx.x;
    const int lane = tid & 63;
    const int wave = tid >> 6;
    const int quad = lane >> 4;
    const int l16 = lane & 15;
    const int q0g = qt * 128 + wave * 32;   // wave's global q base (32 rows)

    s16x8 qf[2][4];
    #pragma unroll
    for (int rt = 0; rt < 2; ++rt) {
        const bf16* qp = Q + (size_t)(b * T_ + q0g + rt * 16 + l16) * QKVSTR + h * HD_ + quad * 8;
        #pragma unroll
        for (int ks = 0; ks < 4; ++ks) qf[rt][ks] = *(const s16x8*)(qp + ks * 32);
    }

    const bf16* Kp = K + (size_t)(b * T_) * QKVSTR + g * HD_;
    const bf16* Vp = Vtg + (size_t)((b * KV_ + g) * HD_) * T_;

    float l_part[2][4] = {};
    f32x4 oacc[2][8] = {};

    const int ntiles = 2 * qt + 2;
    for (int j = 0; j < ntiles; ++j) {
        const int s0 = j * 64;
        __syncthreads();
        #pragma unroll
        for (int i = 0; i < 4; ++i) {
            int g2 = i * 256 + tid;
            int s = g2 >> 4;
            int cs = (g2 & 15) ^ (s & 15);
            gl2lds16(Kp + (size_t)(s0 + s) * QKVSTR + cs * 8, &Kt[g2 * 8]);
        }
        #pragma unroll
        for (int i = 0; i < 4; ++i) {
            int g2 = i * 256 + tid;
            int d = g2 >> 3;
            int cs = (g2 & 7) ^ (d & 7);
            gl2lds16(Vp + (size_t)d * T_ + s0 + cs * 8, &Vt[g2 * 8]);
        }
        __syncthreads();

        // fully-masked wave-tiles on the last diagonal tile: skip compute
        if (s0 > q0g + 31) continue;

        // S = Q K^T  (32 q x 64 s per wave)
        f32x4 sacc[2][4] = {};
        #pragma unroll
        for (int ks = 0; ks < 4; ++ks) {
            #pragma unroll
            for (int ct = 0; ct < 4; ++ct) {
                int srow = ct * 16 + l16;
                int c = (ks * 4 + quad) ^ (srow & 15);
                const s16x8 kf = *(const s16x8*)&Kt[srow * 128 + c * 8];
                #pragma unroll
                for (int rt = 0; rt < 2; ++rt)
                    sacc[rt][ct] = __builtin_amdgcn_mfma_f32_16x16x32_bf16(
                        qf[rt][ks], kf, sacc[rt][ct], 0, 0, 0);
            }
        }

        // static softmax: P = exp2(s) (scale folded into Wq); masked -> 0
        const bool diag = (j >= 2 * qt);
        #pragma unroll
        for (int rt = 0; rt < 2; ++rt) {
            #pragma unroll
            for (int r = 0; r < 4; ++r) {
                const int qrow = q0g + rt * 16 + quad * 4 + r;
                if (diag) {
                    #pragma unroll
                    for (int ct = 0; ct < 4; ++ct)
                        if (s0 + ct * 16 + l16 > qrow) sacc[rt][ct][r] = -INFINITY;
                }
                float psum = 0.f;
                #pragma unroll
                for (int ct = 0; ct < 4; ++ct) {
                    float p = exp2f(sacc[rt][ct][r]);
                    sacc[rt][ct][r] = p;
                    psum += p;
                }
                l_part[rt][r] += psum;
            }
        }

        // P -> LDS (wave-private rows, stride 72)
        #pragma unroll
        for (int rt = 0; rt < 2; ++rt)
            #pragma unroll
            for (int ct = 0; ct < 4; ++ct)
                #pragma unroll
                for (int r = 0; r < 4; ++r)
                    PsOb[(wave * 32 + rt * 16 + quad * 4 + r) * 72 + ct * 16 + l16] =
                        f2bf(sacc[rt][ct][r]);

        // O^T += V^T P^T
        #pragma unroll
        for (int kk = 0; kk < 2; ++kk) {
            s16x8 pf[2];
            #pragma unroll
            for (int rt = 0; rt < 2; ++rt)
                pf[rt] = *(const s16x8*)&PsOb[(wave * 32 + rt * 16 + l16) * 72 + kk * 32 + quad * 8];
            #pragma unroll
            for (int dt = 0; dt < 8; ++dt) {
                int d = dt * 16 + l16;
                int c = (kk * 4 + quad) ^ (d & 7);
                const s16x8 vf = *(const s16x8*)&Vt[d * 64 + c * 8];
                #pragma unroll
                for (int rt = 0; rt < 2; ++rt)
                    oacc[rt][dt] = __builtin_amdgcn_mfma_f32_16x16x32_bf16(
                        vf, pf[rt], oacc[rt][dt], 0, 0, 0);
            }
        }
    }

    // final l: shfl-reduce over 16 lanes, transpose via wave-private lbuf
    #pragma unroll
    for (int rt = 0; rt < 2; ++rt)
        #pragma unroll
        for (int r = 0; r < 4; ++r) {
            float v = l_part[rt][r];
            v += __shfl_xor(v, 1);
            v += __shfl_xor(v, 2);
            v += __shfl_xor(v, 4);
            v += __shfl_xor(v, 8);
            l_part[rt][r] = v;
        }
    if (l16 == 0) {
        #pragma unroll
        for (int rt = 0; rt < 2; ++rt)
            #pragma unroll
            for (int r = 0; r < 4; ++r)
                lbuf[wave][rt * 16 + quad * 4 + r] = l_part[rt][r];
    }
    float invl[2];
    #pragma unroll
    for (int rt = 0; rt < 2; ++rt) invl[rt] = 1.f / lbuf[wave][rt * 16 + l16];

    // protect cross-wave PsOb alias (Ps view vs Ob view)
    __syncthreads();

    // epilogue: two passes (rt), each un-transposing 64 rows via Ob view
    #pragma unroll
    for (int rt = 0; rt < 2; ++rt) {
        #pragma unroll
        for (int dt = 0; dt < 8; ++dt) {
            short tmp[4];
            #pragma unroll
            for (int r = 0; r < 4; ++r) tmp[r] = f2bf(oacc[rt][dt][r] * invl[rt]);
            *(long long*)&PsOb[(wave * 16 + l16) * 136 + dt * 16 + quad * 4] =
                *(const long long*)tmp;
        }
        const int rr = lane >> 2;
        bf16* op = O + (size_t)(b * T_ + qt * 128 + wave * 32 + rt * 16 + rr) * (H_ * HD_) + h * HD_;
        #pragma unroll
        for (int c = 0; c < 4; ++c) {
            int chunk = c * 4 + (lane & 3);
            *(s16x8*)(op + chunk * 8) = *(const s16x8*)&PsOb[(wave * 16 + rr) * 136 + chunk * 8];
        }
    }
}

extern "C" void kernel_launch(void* const* d_in, const int* in_sizes, int n_in,
                              void* d_out, int out_size, void* d_ws, size_t ws_size,
                              hipStream_t stream) {
    const float* x  = (const float*)d_in[0];
    const float* Wq = (const float*)d_in[1];
    const float* Wk = (const float*)d_in[2];
    const float* Wv = (const float*)d_in[3];
    const float* Wo = (const float*)d_in[4];
    float* out = (float*)d_out;

    const size_t NR = (size_t)B_ * T_;               // 4096
    bf16* ws = (bf16*)d_ws;
    bf16* xb    = ws;                                 // 4096*2048
    bf16* Wqkvt = xb + NR * D_;                       // 3072*2048
    bf16* Wot   = Wqkvt + (size_t)QKVSTR * D_;        // 2048*2048
    bf16* QKVb  = Wot + (size_t)D_ * D_;              // 4096*3072
    bf16* Vtg   = QKVb + NR * QKVSTR;                 // 2*4*128*2048
    bf16* Ab    = Vtg + (size_t)B_ * KV_ * HD_ * T_;  // 4096*2048

    const float qscale = 1.4426950408889634f / sqrtf((float)HD_);

    prep<<<6656, 256, 0, stream>>>(x, Wq, Wk, Wv, Wo, xb, Wqkvt, Wot, qscale);

    gemm_nt<bf16, 0><<<dim3(QKVSTR / 128, NR / 128), 256, 0, stream>>>(
        xb, Wqkvt, QKVb, (int)NR, QKVSTR, D_);

    transpose_v<<<dim3(T_ / 64, 8, B_), 256, 0, stream>>>(QKVb + 2560, Vtg);

    flash4<<<dim3(H_, 32), 256, 0, stream>>>(QKVb, QKVb + 2048, Vtg, Ab);

    gemm_nt<float, 1><<<dim3(D_ / 128, NR / 128), 256, 0, stream>>>(
        Ab, Wot, out, (int)NR, D_, H_ * HD_);
}

// Round 9
// 317.376 us; speedup vs baseline: 1.4972x; 1.4972x over previous
//
#include <hip/hip_runtime.h>
#include <hip/hip_bf16.h>
#include <math.h>

#define B_ 2
#define T_ 2048
#define D_ 2048
#define H_ 16
#define KV_ 4
#define HD_ 128
#define REP_ 4
#define QKVSTR 3072

typedef __attribute__((ext_vector_type(8))) short s16x8;
typedef __attribute__((ext_vector_type(4))) float f32x4;
typedef __hip_bfloat16 bf16;

__device__ __forceinline__ short f2bf(float x) {
    bf16 h = __float2bfloat16(x);
    return *reinterpret_cast<short*>(&h);
}

__device__ __forceinline__ void gl2lds16(const void* g, void* l) {
    __builtin_amdgcn_global_load_lds(
        (const __attribute__((address_space(1))) char*)g,
        (__attribute__((address_space(3))) char*)l, 16, 0, 0);
}

// ---------------- fused prep: cast x -> bf16  +  all 4 weight transposes ----
__global__ __launch_bounds__(256) void prep(const float* __restrict__ x,
                                            const float* __restrict__ Wq,
                                            const float* __restrict__ Wk,
                                            const float* __restrict__ Wv,
                                            const float* __restrict__ Wo,
                                            bf16* __restrict__ xb,
                                            bf16* __restrict__ Wqkvt,
                                            bf16* __restrict__ Wot,
                                            float qscale) {
    const int bid = blockIdx.x;
    const int t = threadIdx.x;
    if (bid < 4096) {
        int i = (bid * 256 + t) * 8;
        float4 a = *(const float4*)(x + i);
        float4 b = *(const float4*)(x + i + 4);
        short o[8] = {f2bf(a.x), f2bf(a.y), f2bf(a.z), f2bf(a.w),
                      f2bf(b.x), f2bf(b.y), f2bf(b.z), f2bf(b.w)};
        *(s16x8*)(xb + i) = *(const s16x8*)o;
        return;
    }
    __shared__ short tile[64 * 72];
    const float* W; bf16* dst; int N; float scale; int seg;
    if (bid < 5120)      { seg = bid - 4096; W = Wq; dst = Wqkvt;                      N = 2048; scale = qscale; }
    else if (bid < 5376) { seg = bid - 5120; W = Wk; dst = Wqkvt + (size_t)2048 * D_;  N = 512;  scale = 1.f; }
    else if (bid < 5632) { seg = bid - 5376; W = Wv; dst = Wqkvt + (size_t)2560 * D_;  N = 512;  scale = 1.f; }
    else                 { seg = bid - 5632; W = Wo; dst = Wot;                        N = 2048; scale = 1.f; }
    const int k0 = (seg & 31) * 64, n0 = (seg >> 5) * 64;
    const int r = t >> 2, c0 = (t & 3) * 16;
    const float* src = W + (size_t)(k0 + r) * N + n0 + c0;
    #pragma unroll
    for (int i = 0; i < 16; i += 4) {
        float4 v = *(const float4*)(src + i);
        tile[r * 72 + c0 + i + 0] = f2bf(v.x * scale);
        tile[r * 72 + c0 + i + 1] = f2bf(v.y * scale);
        tile[r * 72 + c0 + i + 2] = f2bf(v.z * scale);
        tile[r * 72 + c0 + i + 3] = f2bf(v.w * scale);
    }
    __syncthreads();
    short tmp[16];
    #pragma unroll
    for (int i = 0; i < 16; ++i) tmp[i] = tile[(c0 + i) * 72 + r];
    bf16* d = dst + (size_t)(n0 + r) * D_ + k0 + c0;
    *(s16x8*)(d)     = *(const s16x8*)&tmp[0];
    *(s16x8*)(d + 8) = *(const s16x8*)&tmp[8];
}

// ---------------- transpose V: Vtg[(b*KV+g)*128+d][t] = V[b*T+t][g*128+d] ----
__global__ __launch_bounds__(256) void transpose_v(const bf16* __restrict__ V,
                                                   bf16* __restrict__ Vtg) {
    __shared__ short tile[64 * 72];
    const int t0 = blockIdx.x * 64;
    const int g = blockIdx.y >> 1;
    const int dp = (blockIdx.y & 1) * 64;
    const int b = blockIdx.z;
    const int t = threadIdx.x;
    const int r = t >> 2, c0 = (t & 3) * 16;
    const bf16* src = V + (size_t)(b * T_ + t0 + r) * QKVSTR + g * HD_ + dp + c0;
    *(s16x8*)&tile[r * 72 + c0]     = *(const s16x8*)(src);
    *(s16x8*)&tile[r * 72 + c0 + 8] = *(const s16x8*)(src + 8);
    __syncthreads();
    const int d = t >> 2, tc = (t & 3) * 16;
    short tmp[16];
    #pragma unroll
    for (int i = 0; i < 16; ++i) tmp[i] = tile[(tc + i) * 72 + d];
    bf16* dst = Vtg + (size_t)((b * KV_ + g) * HD_ + dp + d) * T_ + t0 + tc;
    *(s16x8*)(dst)     = *(const s16x8*)&tmp[0];
    *(s16x8*)(dst + 8) = *(const s16x8*)&tmp[8];
}

// ---------------- bf16 NT GEMM: C[M,N] = A[M,K] * Bt[N,K]^T ----------------
template<typename OUTT, int ROUND>
__global__ __launch_bounds__(256) void gemm_nt(const bf16* __restrict__ A,
                                               const bf16* __restrict__ Bt,
                                               OUTT* __restrict__ C,
                                               int M, int N, int K) {
    __shared__ short As[128 * 64];
    __shared__ short Bs[128 * 64];
    const int tid = threadIdx.x;
    const int lane = tid & 63;
    const int wave = tid >> 6;
    const int quad = lane >> 4;
    const int l16 = lane & 15;
    const int wr = wave >> 1, wc = wave & 1;
    const int row0 = blockIdx.y * 128;
    const int col0 = blockIdx.x * 128;

    f32x4 acc[4][4] = {};

    for (int k0 = 0; k0 < K; k0 += 64) {
        __syncthreads();
        #pragma unroll
        for (int i = 0; i < 4; ++i) {
            int g = i * 256 + tid;
            int row = g >> 3;
            int cs = (g & 7) ^ (row & 7);
            gl2lds16(A + (size_t)(row0 + row) * K + k0 + cs * 8, &As[g * 8]);
        }
        #pragma unroll
        for (int i = 0; i < 4; ++i) {
            int g = i * 256 + tid;
            int row = g >> 3;
            int cs = (g & 7) ^ (row & 7);
            gl2lds16(Bt + (size_t)(col0 + row) * K + k0 + cs * 8, &Bs[g * 8]);
        }
        __syncthreads();
        #pragma unroll
        for (int kk = 0; kk < 2; ++kk) {
            s16x8 af[4], bfr[4];
            #pragma unroll
            for (int i = 0; i < 4; ++i) {
                int row = wr * 64 + i * 16 + l16;
                int c = (kk * 4 + quad) ^ (row & 7);
                af[i] = *(const s16x8*)&As[row * 64 + c * 8];
            }
            #pragma unroll
            for (int j = 0; j < 4; ++j) {
                int row = wc * 64 + j * 16 + l16;
                int c = (kk * 4 + quad) ^ (row & 7);
                bfr[j] = *(const s16x8*)&Bs[row * 64 + c * 8];
            }
            #pragma unroll
            for (int i = 0; i < 4; ++i)
                #pragma unroll
                for (int j = 0; j < 4; ++j)
                    acc[i][j] = __builtin_amdgcn_mfma_f32_16x16x32_bf16(
                        af[i], bfr[j], acc[i][j], 0, 0, 0);
        }
    }

    #pragma unroll
    for (int i = 0; i < 4; ++i) {
        #pragma unroll
        for (int j = 0; j < 4; ++j) {
            #pragma unroll
            for (int r = 0; r < 4; ++r) {
                int row = row0 + wr * 64 + i * 16 + quad * 4 + r;
                int col = col0 + wc * 64 + j * 16 + l16;
                float v = acc[i][j][r];
                if (ROUND) v = rintf(v * 1e4f) * 1e-4f;
                if constexpr (sizeof(OUTT) == 2)
                    C[(size_t)row * N + col] = __float2bfloat16(v);
                else
                    C[(size_t)row * N + col] = v;
            }
        }
    }
}

// ---------------- MFMA flash attention v4b ----------------
// BQ=128 (32 q-rows/wave via rt=2), BKV=64, static softmax (exp2, no max).
// __launch_bounds__(256,2): ~180 VGPRs of live state (qf 32 + oacc 64 +
// sacc 32 + temps) MUST NOT spill — (256,3)'s 170-reg cap caused a 150 B/
// thread/tile scratch spill in round 8 (FETCH+WRITE blew up 10x).
__global__ __launch_bounds__(256, 2) void flash4(const bf16* __restrict__ Q,
                                                 const bf16* __restrict__ K,
                                                 const bf16* __restrict__ Vtg,
                                                 bf16* __restrict__ O) {
    __shared__ short Kt[64 * 128];     // 16 KB
    __shared__ short Vt[128 * 64];     // 16 KB
    __shared__ short PsOb[128 * 72];   // 18 KB; Ps view 128x72, Ob view 64x136
    __shared__ float lbuf[4][32];

    const int h = blockIdx.x;
    const int b = blockIdx.y & 1;
    const int qt = 15 - (blockIdx.y >> 1);
    const int g = h >> 2;
    const int tid = threadIdx.x;
    const int lane = tid & 63;
    const int wave = tid >> 6;
    const int quad = lane >> 4;
    const int l16 = lane & 15;
    const int q0g = qt * 128 + wave * 32;   // wave's global q base (32 rows)

    s16x8 qf[2][4];
    #pragma unroll
    for (int rt = 0; rt < 2; ++rt) {
        const bf16* qp = Q + (size_t)(b * T_ + q0g + rt * 16 + l16) * QKVSTR + h * HD_ + quad * 8;
        #pragma unroll
        for (int ks = 0; ks < 4; ++ks) qf[rt][ks] = *(const s16x8*)(qp + ks * 32);
    }

    const bf16* Kp = K + (size_t)(b * T_) * QKVSTR + g * HD_;
    const bf16* Vp = Vtg + (size_t)((b * KV_ + g) * HD_) * T_;

    float l_part[2][4] = {};
    f32x4 oacc[2][8] = {};

    const int ntiles = 2 * qt + 2;
    for (int j = 0; j < ntiles; ++j) {
        const int s0 = j * 64;
        __syncthreads();
        #pragma unroll
        for (int i = 0; i < 4; ++i) {
            int g2 = i * 256 + tid;
            int s = g2 >> 4;
            int cs = (g2 & 15) ^ (s & 15);
            gl2lds16(Kp + (size_t)(s0 + s) * QKVSTR + cs * 8, &Kt[g2 * 8]);
        }
        #pragma unroll
        for (int i = 0; i < 4; ++i) {
            int g2 = i * 256 + tid;
            int d = g2 >> 3;
            int cs = (g2 & 7) ^ (d & 7);
            gl2lds16(Vp + (size_t)d * T_ + s0 + cs * 8, &Vt[g2 * 8]);
        }
        __syncthreads();

        // fully-masked wave-tiles on the last diagonal tile: skip compute
        if (s0 > q0g + 31) continue;

        // S = Q K^T  (32 q x 64 s per wave)
        f32x4 sacc[2][4] = {};
        #pragma unroll
        for (int ks = 0; ks < 4; ++ks) {
            #pragma unroll
            for (int ct = 0; ct < 4; ++ct) {
                int srow = ct * 16 + l16;
                int c = (ks * 4 + quad) ^ (srow & 15);
                const s16x8 kf = *(const s16x8*)&Kt[srow * 128 + c * 8];
                #pragma unroll
                for (int rt = 0; rt < 2; ++rt)
                    sacc[rt][ct] = __builtin_amdgcn_mfma_f32_16x16x32_bf16(
                        qf[rt][ks], kf, sacc[rt][ct], 0, 0, 0);
            }
        }

        // static softmax: P = exp2(s) (scale folded into Wq); masked -> 0
        const bool diag = (j >= 2 * qt);
        #pragma unroll
        for (int rt = 0; rt < 2; ++rt) {
            #pragma unroll
            for (int r = 0; r < 4; ++r) {
                const int qrow = q0g + rt * 16 + quad * 4 + r;
                if (diag) {
                    #pragma unroll
                    for (int ct = 0; ct < 4; ++ct)
                        if (s0 + ct * 16 + l16 > qrow) sacc[rt][ct][r] = -INFINITY;
                }
                float psum = 0.f;
                #pragma unroll
                for (int ct = 0; ct < 4; ++ct) {
                    float p = exp2f(sacc[rt][ct][r]);
                    sacc[rt][ct][r] = p;
                    psum += p;
                }
                l_part[rt][r] += psum;
            }
        }

        // P -> LDS (wave-private rows, stride 72)
        #pragma unroll
        for (int rt = 0; rt < 2; ++rt)
            #pragma unroll
            for (int ct = 0; ct < 4; ++ct)
                #pragma unroll
                for (int r = 0; r < 4; ++r)
                    PsOb[(wave * 32 + rt * 16 + quad * 4 + r) * 72 + ct * 16 + l16] =
                        f2bf(sacc[rt][ct][r]);

        // O^T += V^T P^T
        #pragma unroll
        for (int kk = 0; kk < 2; ++kk) {
            s16x8 pf[2];
            #pragma unroll
            for (int rt = 0; rt < 2; ++rt)
                pf[rt] = *(const s16x8*)&PsOb[(wave * 32 + rt * 16 + l16) * 72 + kk * 32 + quad * 8];
            #pragma unroll
            for (int dt = 0; dt < 8; ++dt) {
                int d = dt * 16 + l16;
                int c = (kk * 4 + quad) ^ (d & 7);
                const s16x8 vf = *(const s16x8*)&Vt[d * 64 + c * 8];
                #pragma unroll
                for (int rt = 0; rt < 2; ++rt)
                    oacc[rt][dt] = __builtin_amdgcn_mfma_f32_16x16x32_bf16(
                        vf, pf[rt], oacc[rt][dt], 0, 0, 0);
            }
        }
    }

    // final l: shfl-reduce over 16 lanes, transpose via wave-private lbuf
    #pragma unroll
    for (int rt = 0; rt < 2; ++rt)
        #pragma unroll
        for (int r = 0; r < 4; ++r) {
            float v = l_part[rt][r];
            v += __shfl_xor(v, 1);
            v += __shfl_xor(v, 2);
            v += __shfl_xor(v, 4);
            v += __shfl_xor(v, 8);
            l_part[rt][r] = v;
        }
    if (l16 == 0) {
        #pragma unroll
        for (int rt = 0; rt < 2; ++rt)
            #pragma unroll
            for (int r = 0; r < 4; ++r)
                lbuf[wave][rt * 16 + quad * 4 + r] = l_part[rt][r];
    }
    float invl[2];
    #pragma unroll
    for (int rt = 0; rt < 2; ++rt) invl[rt] = 1.f / lbuf[wave][rt * 16 + l16];

    // protect cross-wave PsOb alias (Ps view vs Ob view)
    __syncthreads();

    // epilogue: two passes (rt), each un-transposing 64 rows via Ob view
    #pragma unroll
    for (int rt = 0; rt < 2; ++rt) {
        #pragma unroll
        for (int dt = 0; dt < 8; ++dt) {
            short tmp[4];
            #pragma unroll
            for (int r = 0; r < 4; ++r) tmp[r] = f2bf(oacc[rt][dt][r] * invl[rt]);
            *(long long*)&PsOb[(wave * 16 + l16) * 136 + dt * 16 + quad * 4] =
                *(const long long*)tmp;
        }
        const int rr = lane >> 2;
        bf16* op = O + (size_t)(b * T_ + qt * 128 + wave * 32 + rt * 16 + rr) * (H_ * HD_) + h * HD_;
        #pragma unroll
        for (int c = 0; c < 4; ++c) {
            int chunk = c * 4 + (lane & 3);
            *(s16x8*)(op + chunk * 8) = *(const s16x8*)&PsOb[(wave * 16 + rr) * 136 + chunk * 8];
        }
    }
}

extern "C" void kernel_launch(void* const* d_in, const int* in_sizes, int n_in,
                              void* d_out, int out_size, void* d_ws, size_t ws_size,
                              hipStream_t stream) {
    const float* x  = (const float*)d_in[0];
    const float* Wq = (const float*)d_in[1];
    const float* Wk = (const float*)d_in[2];
    const float* Wv = (const float*)d_in[3];
    const float* Wo = (const float*)d_in[4];
    float* out = (float*)d_out;

    const size_t NR = (size_t)B_ * T_;               // 4096
    bf16* ws = (bf16*)d_ws;
    bf16* xb    = ws;                                 // 4096*2048
    bf16* Wqkvt = xb + NR * D_;                       // 3072*2048
    bf16* Wot   = Wqkvt + (size_t)QKVSTR * D_;        // 2048*2048
    bf16* QKVb  = Wot + (size_t)D_ * D_;              // 4096*3072
    bf16* Vtg   = QKVb + NR * QKVSTR;                 // 2*4*128*2048
    bf16* Ab    = Vtg + (size_t)B_ * KV_ * HD_ * T_;  // 4096*2048

    const float qscale = 1.4426950408889634f / sqrtf((float)HD_);

    prep<<<6656, 256, 0, stream>>>(x, Wq, Wk, Wv, Wo, xb, Wqkvt, Wot, qscale);

    gemm_nt<bf16, 0><<<dim3(QKVSTR / 128, NR / 128), 256, 0, stream>>>(
        xb, Wqkvt, QKVb, (int)NR, QKVSTR, D_);

    transpose_v<<<dim3(T_ / 64, 8, B_), 256, 0, stream>>>(QKVb + 2560, Vtg);

    flash4<<<dim3(H_, 32), 256, 0, stream>>>(QKVb, QKVb + 2048, Vtg, Ab);

    gemm_nt<float, 1><<<dim3(D_ / 128, NR / 128), 256, 0, stream>>>(
        Ab, Wot, out, (int)NR, D_, H_ * HD_);
}

// Round 10
// 299.915 us; speedup vs baseline: 1.5843x; 1.0582x over previous
//
#include <hip/hip_runtime.h>
#include <hip/hip_bf16.h>
#include <math.h>

#define B_ 2
#define T_ 2048
#define D_ 2048
#define H_ 16
#define KV_ 4
#define HD_ 128
#define REP_ 4
#define QKVSTR 3072

typedef __attribute__((ext_vector_type(8))) short s16x8;
typedef __attribute__((ext_vector_type(4))) float f32x4;
typedef __hip_bfloat16 bf16;

__device__ __forceinline__ short f2bf(float x) {
    bf16 h = __float2bfloat16(x);
    return *reinterpret_cast<short*>(&h);
}

__device__ __forceinline__ void gl2lds16(const void* g, void* l) {
    __builtin_amdgcn_global_load_lds(
        (const __attribute__((address_space(1))) char*)g,
        (__attribute__((address_space(3))) char*)l, 16, 0, 0);
}

// ---------------- fused prep: cast x -> bf16  +  all 4 weight transposes ----
__global__ __launch_bounds__(256) void prep(const float* __restrict__ x,
                                            const float* __restrict__ Wq,
                                            const float* __restrict__ Wk,
                                            const float* __restrict__ Wv,
                                            const float* __restrict__ Wo,
                                            bf16* __restrict__ xb,
                                            bf16* __restrict__ Wqkvt,
                                            bf16* __restrict__ Wot,
                                            float qscale) {
    const int bid = blockIdx.x;
    const int t = threadIdx.x;
    if (bid < 4096) {
        int i = (bid * 256 + t) * 8;
        float4 a = *(const float4*)(x + i);
        float4 b = *(const float4*)(x + i + 4);
        short o[8] = {f2bf(a.x), f2bf(a.y), f2bf(a.z), f2bf(a.w),
                      f2bf(b.x), f2bf(b.y), f2bf(b.z), f2bf(b.w)};
        *(s16x8*)(xb + i) = *(const s16x8*)o;
        return;
    }
    __shared__ short tile[64 * 72];
    const float* W; bf16* dst; int N; float scale; int seg;
    if (bid < 5120)      { seg = bid - 4096; W = Wq; dst = Wqkvt;                      N = 2048; scale = qscale; }
    else if (bid < 5376) { seg = bid - 5120; W = Wk; dst = Wqkvt + (size_t)2048 * D_;  N = 512;  scale = 1.f; }
    else if (bid < 5632) { seg = bid - 5376; W = Wv; dst = Wqkvt + (size_t)2560 * D_;  N = 512;  scale = 1.f; }
    else                 { seg = bid - 5632; W = Wo; dst = Wot;                        N = 2048; scale = 1.f; }
    const int k0 = (seg & 31) * 64, n0 = (seg >> 5) * 64;
    const int r = t >> 2, c0 = (t & 3) * 16;
    const float* src = W + (size_t)(k0 + r) * N + n0 + c0;
    #pragma unroll
    for (int i = 0; i < 16; i += 4) {
        float4 v = *(const float4*)(src + i);
        tile[r * 72 + c0 + i + 0] = f2bf(v.x * scale);
        tile[r * 72 + c0 + i + 1] = f2bf(v.y * scale);
        tile[r * 72 + c0 + i + 2] = f2bf(v.z * scale);
        tile[r * 72 + c0 + i + 3] = f2bf(v.w * scale);
    }
    __syncthreads();
    short tmp[16];
    #pragma unroll
    for (int i = 0; i < 16; ++i) tmp[i] = tile[(c0 + i) * 72 + r];
    bf16* d = dst + (size_t)(n0 + r) * D_ + k0 + c0;
    *(s16x8*)(d)     = *(const s16x8*)&tmp[0];
    *(s16x8*)(d + 8) = *(const s16x8*)&tmp[8];
}

// ---------------- transpose V: Vtg[(b*KV+g)*128+d][t] = V[b*T+t][g*128+d] ----
__global__ __launch_bounds__(256) void transpose_v(const bf16* __restrict__ V,
                                                   bf16* __restrict__ Vtg) {
    __shared__ short tile[64 * 72];
    const int t0 = blockIdx.x * 64;
    const int g = blockIdx.y >> 1;
    const int dp = (blockIdx.y & 1) * 64;
    const int b = blockIdx.z;
    const int t = threadIdx.x;
    const int r = t >> 2, c0 = (t & 3) * 16;
    const bf16* src = V + (size_t)(b * T_ + t0 + r) * QKVSTR + g * HD_ + dp + c0;
    *(s16x8*)&tile[r * 72 + c0]     = *(const s16x8*)(src);
    *(s16x8*)&tile[r * 72 + c0 + 8] = *(const s16x8*)(src + 8);
    __syncthreads();
    const int d = t >> 2, tc = (t & 3) * 16;
    short tmp[16];
    #pragma unroll
    for (int i = 0; i < 16; ++i) tmp[i] = tile[(tc + i) * 72 + d];
    bf16* dst = Vtg + (size_t)((b * KV_ + g) * HD_ + dp + d) * T_ + t0 + tc;
    *(s16x8*)(dst)     = *(const s16x8*)&tmp[0];
    *(s16x8*)(dst + 8) = *(const s16x8*)&tmp[8];
}

// ---------------- bf16 NT GEMM: C[M,N] = A[M,K] * Bt[N,K]^T ----------------
template<typename OUTT, int ROUND>
__global__ __launch_bounds__(256) void gemm_nt(const bf16* __restrict__ A,
                                               const bf16* __restrict__ Bt,
                                               OUTT* __restrict__ C,
                                               int M, int N, int K) {
    __shared__ short As[128 * 64];
    __shared__ short Bs[128 * 64];
    const int tid = threadIdx.x;
    const int lane = tid & 63;
    const int wave = tid >> 6;
    const int quad = lane >> 4;
    const int l16 = lane & 15;
    const int wr = wave >> 1, wc = wave & 1;
    const int row0 = blockIdx.y * 128;
    const int col0 = blockIdx.x * 128;

    f32x4 acc[4][4] = {};

    for (int k0 = 0; k0 < K; k0 += 64) {
        __syncthreads();
        #pragma unroll
        for (int i = 0; i < 4; ++i) {
            int g = i * 256 + tid;
            int row = g >> 3;
            int cs = (g & 7) ^ (row & 7);
            gl2lds16(A + (size_t)(row0 + row) * K + k0 + cs * 8, &As[g * 8]);
        }
        #pragma unroll
        for (int i = 0; i < 4; ++i) {
            int g = i * 256 + tid;
            int row = g >> 3;
            int cs = (g & 7) ^ (row & 7);
            gl2lds16(Bt + (size_t)(col0 + row) * K + k0 + cs * 8, &Bs[g * 8]);
        }
        __syncthreads();
        #pragma unroll
        for (int kk = 0; kk < 2; ++kk) {
            s16x8 af[4], bfr[4];
            #pragma unroll
            for (int i = 0; i < 4; ++i) {
                int row = wr * 64 + i * 16 + l16;
                int c = (kk * 4 + quad) ^ (row & 7);
                af[i] = *(const s16x8*)&As[row * 64 + c * 8];
            }
            #pragma unroll
            for (int j = 0; j < 4; ++j) {
                int row = wc * 64 + j * 16 + l16;
                int c = (kk * 4 + quad) ^ (row & 7);
                bfr[j] = *(const s16x8*)&Bs[row * 64 + c * 8];
            }
            #pragma unroll
            for (int i = 0; i < 4; ++i)
                #pragma unroll
                for (int j = 0; j < 4; ++j)
                    acc[i][j] = __builtin_amdgcn_mfma_f32_16x16x32_bf16(
                        af[i], bfr[j], acc[i][j], 0, 0, 0);
        }
    }

    #pragma unroll
    for (int i = 0; i < 4; ++i) {
        #pragma unroll
        for (int j = 0; j < 4; ++j) {
            #pragma unroll
            for (int r = 0; r < 4; ++r) {
                int row = row0 + wr * 64 + i * 16 + quad * 4 + r;
                int col = col0 + wc * 64 + j * 16 + l16;
                float v = acc[i][j][r];
                if (ROUND) v = rintf(v * 1e4f) * 1e-4f;
                if constexpr (sizeof(OUTT) == 2)
                    C[(size_t)row * N + col] = __float2bfloat16(v);
                else
                    C[(size_t)row * N + col] = v;
            }
        }
    }
}

// ---------------- MFMA flash attention v5 ----------------
// BQ=64 per block, TWO waves x 32 q-rows (rt=2), 128-thread blocks.
// Grid (H, 64) = 1024 blocks, heavy-qt-first (LPT balance), ~3 blocks/CU
// (42 KB LDS). Same per-wave state as v4 (~128 VGPR, no spill at bounds
// (128,2)). Static softmax (exp2, scale folded into Wq).
__global__ __launch_bounds__(128, 2) void flash5(const bf16* __restrict__ Q,
                                                 const bf16* __restrict__ K,
                                                 const bf16* __restrict__ Vtg,
                                                 bf16* __restrict__ O) {
    __shared__ short Kt[64 * 128];    // 16 KB
    __shared__ short Vt[128 * 64];    // 16 KB
    __shared__ short PsOb[64 * 72];   // 9 KB; Ps view 64x72, Ob view 32x136
    __shared__ float lbuf[2][32];

    const int h = blockIdx.x;
    const int b = blockIdx.y & 1;
    const int qt = 31 - (blockIdx.y >> 1);
    const int g = h >> 2;
    const int tid = threadIdx.x;
    const int lane = tid & 63;
    const int wave = tid >> 6;          // 0..1
    const int quad = lane >> 4;
    const int l16 = lane & 15;
    const int q0g = qt * 64 + wave * 32;   // wave's global q base (32 rows)

    s16x8 qf[2][4];
    #pragma unroll
    for (int rt = 0; rt < 2; ++rt) {
        const bf16* qp = Q + (size_t)(b * T_ + q0g + rt * 16 + l16) * QKVSTR + h * HD_ + quad * 8;
        #pragma unroll
        for (int ks = 0; ks < 4; ++ks) qf[rt][ks] = *(const s16x8*)(qp + ks * 32);
    }

    const bf16* Kp = K + (size_t)(b * T_) * QKVSTR + g * HD_;
    const bf16* Vp = Vtg + (size_t)((b * KV_ + g) * HD_) * T_;

    float l_part[2][4] = {};
    f32x4 oacc[2][8] = {};

    for (int j = 0; j <= qt; ++j) {
        const int s0 = j * 64;
        __syncthreads();
        #pragma unroll
        for (int i = 0; i < 8; ++i) {
            int g2 = i * 128 + tid;
            int s = g2 >> 4;
            int cs = (g2 & 15) ^ (s & 15);
            gl2lds16(Kp + (size_t)(s0 + s) * QKVSTR + cs * 8, &Kt[g2 * 8]);
        }
        #pragma unroll
        for (int i = 0; i < 8; ++i) {
            int g2 = i * 128 + tid;
            int d = g2 >> 3;
            int cs = (g2 & 7) ^ (d & 7);
            gl2lds16(Vp + (size_t)d * T_ + s0 + cs * 8, &Vt[g2 * 8]);
        }
        __syncthreads();

        // S = Q K^T  (32 q x 64 s per wave)
        f32x4 sacc[2][4] = {};
        #pragma unroll
        for (int ks = 0; ks < 4; ++ks) {
            #pragma unroll
            for (int ct = 0; ct < 4; ++ct) {
                int srow = ct * 16 + l16;
                int c = (ks * 4 + quad) ^ (srow & 15);
                const s16x8 kf = *(const s16x8*)&Kt[srow * 128 + c * 8];
                #pragma unroll
                for (int rt = 0; rt < 2; ++rt)
                    sacc[rt][ct] = __builtin_amdgcn_mfma_f32_16x16x32_bf16(
                        qf[rt][ks], kf, sacc[rt][ct], 0, 0, 0);
            }
        }

        // static softmax: P = exp2(s) (scale folded into Wq); masked -> 0
        const bool diag = (j == qt);
        #pragma unroll
        for (int rt = 0; rt < 2; ++rt) {
            #pragma unroll
            for (int r = 0; r < 4; ++r) {
                const int qrow = q0g + rt * 16 + quad * 4 + r;
                if (diag) {
                    #pragma unroll
                    for (int ct = 0; ct < 4; ++ct)
                        if (s0 + ct * 16 + l16 > qrow) sacc[rt][ct][r] = -INFINITY;
                }
                float psum = 0.f;
                #pragma unroll
                for (int ct = 0; ct < 4; ++ct) {
                    float p = exp2f(sacc[rt][ct][r]);
                    sacc[rt][ct][r] = p;
                    psum += p;
                }
                l_part[rt][r] += psum;
            }
        }

        // P -> LDS (wave-private rows, stride 72)
        #pragma unroll
        for (int rt = 0; rt < 2; ++rt)
            #pragma unroll
            for (int ct = 0; ct < 4; ++ct)
                #pragma unroll
                for (int r = 0; r < 4; ++r)
                    PsOb[(wave * 32 + rt * 16 + quad * 4 + r) * 72 + ct * 16 + l16] =
                        f2bf(sacc[rt][ct][r]);

        // O^T += V^T P^T
        #pragma unroll
        for (int kk = 0; kk < 2; ++kk) {
            s16x8 pf[2];
            #pragma unroll
            for (int rt = 0; rt < 2; ++rt)
                pf[rt] = *(const s16x8*)&PsOb[(wave * 32 + rt * 16 + l16) * 72 + kk * 32 + quad * 8];
            #pragma unroll
            for (int dt = 0; dt < 8; ++dt) {
                int d = dt * 16 + l16;
                int c = (kk * 4 + quad) ^ (d & 7);
                const s16x8 vf = *(const s16x8*)&Vt[d * 64 + c * 8];
                #pragma unroll
                for (int rt = 0; rt < 2; ++rt)
                    oacc[rt][dt] = __builtin_amdgcn_mfma_f32_16x16x32_bf16(
                        vf, pf[rt], oacc[rt][dt], 0, 0, 0);
            }
        }
    }

    // final l: shfl-reduce over 16 lanes, transpose via wave-private lbuf
    #pragma unroll
    for (int rt = 0; rt < 2; ++rt)
        #pragma unroll
        for (int r = 0; r < 4; ++r) {
            float v = l_part[rt][r];
            v += __shfl_xor(v, 1);
            v += __shfl_xor(v, 2);
            v += __shfl_xor(v, 4);
            v += __shfl_xor(v, 8);
            l_part[rt][r] = v;
        }
    if (l16 == 0) {
        #pragma unroll
        for (int rt = 0; rt < 2; ++rt)
            #pragma unroll
            for (int r = 0; r < 4; ++r)
                lbuf[wave][rt * 16 + quad * 4 + r] = l_part[rt][r];
    }
    float invl[2];
    #pragma unroll
    for (int rt = 0; rt < 2; ++rt) invl[rt] = 1.f / lbuf[wave][rt * 16 + l16];

    // protect cross-wave PsOb alias (Ps view vs Ob view)
    __syncthreads();

    // epilogue: two passes (rt), each un-transposing 32 rows via Ob view
    #pragma unroll
    for (int rt = 0; rt < 2; ++rt) {
        #pragma unroll
        for (int dt = 0; dt < 8; ++dt) {
            short tmp[4];
            #pragma unroll
            for (int r = 0; r < 4; ++r) tmp[r] = f2bf(oacc[rt][dt][r] * invl[rt]);
            *(long long*)&PsOb[(wave * 16 + l16) * 136 + dt * 16 + quad * 4] =
                *(const long long*)tmp;
        }
        const int rr = lane >> 2;
        bf16* op = O + (size_t)(b * T_ + qt * 64 + wave * 32 + rt * 16 + rr) * (H_ * HD_) + h * HD_;
        #pragma unroll
        for (int c = 0; c < 4; ++c) {
            int chunk = c * 4 + (lane & 3);
            *(s16x8*)(op + chunk * 8) = *(const s16x8*)&PsOb[(wave * 16 + rr) * 136 + chunk * 8];
        }
    }
}

extern "C" void kernel_launch(void* const* d_in, const int* in_sizes, int n_in,
                              void* d_out, int out_size, void* d_ws, size_t ws_size,
                              hipStream_t stream) {
    const float* x  = (const float*)d_in[0];
    const float* Wq = (const float*)d_in[1];
    const float* Wk = (const float*)d_in[2];
    const float* Wv = (const float*)d_in[3];
    const float* Wo = (const float*)d_in[4];
    float* out = (float*)d_out;

    const size_t NR = (size_t)B_ * T_;               // 4096
    bf16* ws = (bf16*)d_ws;
    bf16* xb    = ws;                                 // 4096*2048
    bf16* Wqkvt = xb + NR * D_;                       // 3072*2048
    bf16* Wot   = Wqkvt + (size_t)QKVSTR * D_;        // 2048*2048
    bf16* QKVb  = Wot + (size_t)D_ * D_;              // 4096*3072
    bf16* Vtg   = QKVb + NR * QKVSTR;                 // 2*4*128*2048
    bf16* Ab    = Vtg + (size_t)B_ * KV_ * HD_ * T_;  // 4096*2048

    const float qscale = 1.4426950408889634f / sqrtf((float)HD_);

    prep<<<6656, 256, 0, stream>>>(x, Wq, Wk, Wv, Wo, xb, Wqkvt, Wot, qscale);

    gemm_nt<bf16, 0><<<dim3(QKVSTR / 128, NR / 128), 256, 0, stream>>>(
        xb, Wqkvt, QKVb, (int)NR, QKVSTR, D_);

    transpose_v<<<dim3(T_ / 64, 8, B_), 256, 0, stream>>>(QKVb + 2560, Vtg);

    flash5<<<dim3(H_, 64), 128, 0, stream>>>(QKVb, QKVb + 2048, Vtg, Ab);

    gemm_nt<float, 1><<<dim3(D_ / 128, NR / 128), 256, 0, stream>>>(
        Ab, Wot, out, (int)NR, D_, H_ * HD_);
}